// Round 4
// baseline (1305.046 us; speedup 1.0000x reference)
//
#include <hip/hip_runtime.h>

#define NN 200
#define CCH 32
#define OC 64
#define JC 6400     // NN*CCH
#define KF 96       // 3*CCH
#define MC 192      // 3*OC

// ---------------- prep ----------------
__global__ __launch_bounds__(256) void k_sums(const float* adj, float* cs, float* rs) {
    int t = blockIdx.x * 256 + threadIdx.x;
    if (t < NN) {
        float c = 0.f, r = 0.f;
        for (int p = 0; p < NN; ++p) {
            if (p != t) {
                c += adj[p * NN + t];
                r += adj[t * NN + p];
            }
        }
        cs[t] = c; rs[t] = r;
    }
}

__global__ __launch_bounds__(256) void k_lap(const float* adj, const float* cs, const float* rs,
                                             float* L, float* Lt) {
    int idx = blockIdx.x * 256 + threadIdx.x;
    if (idx < NN * NN) {
        int p = idx / NN, q = idx - p * NN;
        float a = (p == q) ? 0.f : adj[idx];
        float d0 = (cs[p] > 0.f) ? rsqrtf(cs[p]) : 0.f;
        float d1 = (rs[q] > 0.f) ? rsqrtf(rs[q]) : 0.f;
        float v = d0 * a * d1;
        L[idx] = v;             // L[p][q]
        Lt[q * NN + p] = v;     // Lt[e][j] = L[j][e]
    }
}

// C2 = 2*L*L - I ; C2T = transpose(C2)
__global__ __launch_bounds__(256) void k_sq(const float* L, float* C2, float* C2T) {
    int idx = blockIdx.x * 256 + threadIdx.x;
    if (idx < NN * NN) {
        int p = idx / NN, q = idx - p * NN;
        float s = 0.f;
        for (int r = 0; r < NN; ++r) s += L[p * NN + r] * L[r * NN + q];
        float v = 2.f * s - ((p == q) ? 1.f : 0.f);
        C2[idx] = v;
        C2T[q * NN + p] = v;
    }
}

// Wm[k1*32+c][k2*64+o] = w[o][(k1*3+k2)*32+c]
__global__ __launch_bounds__(256) void k_wprep(const float* w, float* Wm) {
    int idx = blockIdx.x * 256 + threadIdx.x;
    if (idx < KF * MC) {
        int row = idx / MC, col = idx - row * MC;
        int k1 = row >> 5, c = row & 31;
        int k2 = col >> 6, o = col & 63;
        Wm[idx] = w[o * 288 + (k1 * 3 + k2) * 32 + c];
    }
}

// ---------------- stage 1: Y1[t][e][c] = sum_b M1[b][i] X[a][b][e][c]; Y2 with M2.
// t = z*Gi + il, i = i0 + il, a = a0 + z.
__global__ __launch_bounds__(256)
void k_y(const float* M1, const float* M2, const float* x,
         float* Y1, float* Y2, int a0, int i0, int Gi) {
    int z = blockIdx.z;
    int ib = blockIdx.y * 32;
    int jc0 = blockIdx.x * 128;
    int tid = threadIdx.x;
    int tx = tid & 31, ty = tid >> 5;   // ty 0..7

    __shared__ float M1s[16][32];
    __shared__ float M2s[16][32];
    __shared__ float Xs[16][128];

    const float* xb = x + (size_t)(a0 + z) * NN * JC;
    float acc1[4][4] = {}, acc2[4][4] = {};

    for (int k0 = 0; k0 < NN; k0 += 16) {
        __syncthreads();
        for (int f = tid; f < 512; f += 256) {
            int bb = f >> 5, ii = f & 31;
            int b = k0 + bb, i = i0 + ib + ii;
            float m1 = 0.f, m2 = 0.f;
            if (b < NN && i < NN) { m1 = M1[b * NN + i]; m2 = M2[b * NN + i]; }
            M1s[bb][ii] = m1; M2s[bb][ii] = m2;
        }
        for (int f = tid; f < 2048; f += 256) {
            int bb = f >> 7, jj = f & 127;
            int b = k0 + bb;
            Xs[bb][jj] = (b < NN) ? xb[(size_t)b * JC + jc0 + jj] : 0.f;
        }
        __syncthreads();
        for (int kk = 0; kk < 16; ++kk) {
            float xv[4];
            for (int q = 0; q < 4; ++q) xv[q] = Xs[kk][tx * 4 + q];
            for (int r = 0; r < 4; ++r) {
                float m1 = M1s[kk][ty * 4 + r];
                float m2 = M2s[kk][ty * 4 + r];
                for (int q = 0; q < 4; ++q) {
                    acc1[r][q] += m1 * xv[q];
                    acc2[r][q] += m2 * xv[q];
                }
            }
        }
    }
    for (int r = 0; r < 4; ++r) {
        int il = ib + ty * 4 + r;
        if (il < Gi) {
            size_t base = (size_t)(z * Gi + il) * JC + jc0 + tx * 4;
            for (int q = 0; q < 4; ++q) {
                Y1[base + q] = acc1[r][q];
                Y2[base + q] = acc2[r][q];
            }
        }
    }
}

// ---------------- stage 2: per row (t,e): [D|E1|E2](o) = sum_{k1,c} U[k1,c] * Wm[k1*32+c][k2*64+o]
// U = [X_row(i) | Y1_row | Y2_row]
__global__ __launch_bounds__(256)
void k_mix2(const float* x, const float* Y1, const float* Y2, const float* Wm,
            float* Dm, float* E1, float* E2, int a0, int i0, int Gi) {
    int t = blockIdx.y;
    int e0b = blockIdx.x * 32;
    int a = t / Gi, il = t - a * Gi;
    int tid = threadIdx.x;
    int tx = tid & 63, ty = tid >> 6;   // ty 0..3

    __shared__ float Us[32][KF];
    __shared__ float Ws[16][MC];

    const float* x_row  = x  + ((size_t)(a0 + a) * NN + (i0 + il)) * JC;
    const float* y1_row = Y1 + (size_t)t * JC;
    const float* y2_row = Y2 + (size_t)t * JC;

    for (int f = tid; f < 1024; f += 256) {
        int er = f >> 5, c = f & 31;
        int e = e0b + er;
        float v0 = 0.f, v1 = 0.f, v2 = 0.f;
        if (e < NN) {
            v0 = x_row[e * CCH + c];
            v1 = y1_row[e * CCH + c];
            v2 = y2_row[e * CCH + c];
        }
        Us[er][c] = v0;
        Us[er][32 + c] = v1;
        Us[er][64 + c] = v2;
    }

    float acc[8][3] = {};
    for (int k0 = 0; k0 < KF; k0 += 16) {
        __syncthreads();
        for (int f = tid; f < 16 * MC; f += 256) {
            int kk = f / MC, cc = f - kk * MC;
            Ws[kk][cc] = Wm[(k0 + kk) * MC + cc];
        }
        __syncthreads();
        for (int kk = 0; kk < 16; ++kk) {
            float w0 = Ws[kk][tx], w1 = Ws[kk][64 + tx], w2 = Ws[kk][128 + tx];
            for (int rr = 0; rr < 8; ++rr) {
                float u = Us[ty + rr * 4][k0 + kk];
                acc[rr][0] += u * w0;
                acc[rr][1] += u * w1;
                acc[rr][2] += u * w2;
            }
        }
    }
    for (int rr = 0; rr < 8; ++rr) {
        int e = e0b + ty + rr * 4;
        if (e < NN) {
            size_t base = (size_t)t * (NN * OC) + (size_t)e * OC + tx;
            Dm[base] = acc[rr][0];
            E1[base] = acc[rr][1];
            E2[base] = acc[rr][2];
        }
    }
}

// ---------------- stage 3: out[a][i][j][o] = bias[o] + D[t][j][o]
//                       + sum_e B1T[e][j]*E1[t][e][o] + sum_e B2T[e][j]*E2[t][e][o]
__global__ __launch_bounds__(256)
void k_out(const float* B1T, const float* B2T, const float* Dm, const float* E1,
           const float* E2, const float* bias, float* out, int a0, int i0, int Gi) {
    int t = blockIdx.x;
    int a = t / Gi, il = t - a * Gi;
    int tid = threadIdx.x;
    int tx = tid & 15, ty = tid >> 4;   // ty 0..15

    __shared__ float E1s[10][64];
    __shared__ float E2s[10][64];
    __shared__ float B1s[10][208];
    __shared__ float B2s[10][208];

    for (int f = tid; f < 80; f += 256) {
        int ee = f >> 3, pp = f & 7;
        B1s[ee][200 + pp] = 0.f;
        B2s[ee][200 + pp] = 0.f;
    }

    const float* e1b = E1 + (size_t)t * (NN * OC);
    const float* e2b = E2 + (size_t)t * (NN * OC);

    float acc[13][4] = {};
    for (int e0 = 0; e0 < NN; e0 += 10) {
        __syncthreads();
        for (int f = tid; f < 640; f += 256) {
            int ee = f >> 6, oo = f & 63;
            E1s[ee][oo] = e1b[(size_t)(e0 + ee) * OC + oo];
            E2s[ee][oo] = e2b[(size_t)(e0 + ee) * OC + oo];
        }
        for (int f = tid; f < 2000; f += 256) {
            int ee = f / 200, jj = f - ee * 200;
            B1s[ee][jj] = B1T[(e0 + ee) * NN + jj];
            B2s[ee][jj] = B2T[(e0 + ee) * NN + jj];
        }
        __syncthreads();
        for (int ee = 0; ee < 10; ++ee) {
            float p1[4], p2[4];
            for (int q = 0; q < 4; ++q) { p1[q] = E1s[ee][tx * 4 + q]; p2[q] = E2s[ee][tx * 4 + q]; }
            for (int jj = 0; jj < 13; ++jj) {
                float b1 = B1s[ee][ty + 16 * jj];
                float b2 = B2s[ee][ty + 16 * jj];
                for (int q = 0; q < 4; ++q) acc[jj][q] += b1 * p1[q] + b2 * p2[q];
            }
        }
    }

    float bv[4];
    for (int q = 0; q < 4; ++q) bv[q] = bias[tx * 4 + q];

    const float* db = Dm + (size_t)t * (NN * OC);
    float* ob = out + ((size_t)(a0 + a) * NN + (i0 + il)) * NN * OC;
    for (int jj = 0; jj < 13; ++jj) {
        int j = ty + 16 * jj;
        if (j < NN) {
            for (int q = 0; q < 4; ++q) {
                ob[(size_t)j * OC + tx * 4 + q] =
                    acc[jj][q] + bv[q] + db[(size_t)j * OC + tx * 4 + q];
            }
        }
    }
}

extern "C" void kernel_launch(void* const* d_in, const int* in_sizes, int n_in,
                              void* d_out, int out_size, void* d_ws, size_t ws_size,
                              hipStream_t stream) {
    const float* x    = (const float*)d_in[0];   // [8,200,200,32] fp32
    const float* adj  = (const float*)d_in[1];   // [200,200] fp32
    const float* w    = (const float*)d_in[2];   // [64,288] fp32
    const float* bias = (const float*)d_in[3];   // [64] fp32
    float* out = (float*)d_out;                  // [8,200,200,64] fp32

    char* ws = (char*)d_ws;
    size_t off = 0;
    auto alloc = [&](size_t bytes) { size_t p = off; off = (off + bytes + 255) & ~(size_t)255; return p; };
    float* cs  = (float*)(ws + alloc(NN * 4));
    float* rs  = (float*)(ws + alloc(NN * 4));
    float* L   = (float*)(ws + alloc(NN * NN * 4));
    float* Lt  = (float*)(ws + alloc(NN * NN * 4));
    float* C2  = (float*)(ws + alloc(NN * NN * 4));
    float* C2T = (float*)(ws + alloc(NN * NN * 4));
    float* Wm  = (float*)(ws + alloc(KF * MC * 4));
    size_t fixedEnd = off;

    // pick chunk config: Ab batches x Gi i-rows at a time.
    // bytes per (a,i) row: 2*JC*4 (Y1,Y2) + 3*NN*OC*4 (D,E1,E2) = 204800
    const int cfgA[10] = {8, 8, 8, 8, 4, 2, 1, 1, 1, 1};
    const int cfgG[10] = {200, 100, 50, 25, 25, 25, 25, 10, 5, 1};
    int Ab = 1, Gi = 1;
    for (int k = 0; k < 10; ++k) {
        size_t need = fixedEnd + (size_t)cfgA[k] * cfgG[k] * 204800;
        if (need <= ws_size) { Ab = cfgA[k]; Gi = cfgG[k]; break; }
    }

    size_t yB = (size_t)Ab * Gi * JC * 4;        // bytes per Y tensor
    size_t vB = (size_t)Ab * Gi * NN * OC * 4;   // bytes per D/E tensor
    float* Y1 = (float*)(ws + fixedEnd);
    float* Y2 = (float*)(ws + fixedEnd + yB);
    float* Dm = (float*)(ws + fixedEnd + 2 * yB);
    float* E1 = (float*)(ws + fixedEnd + 2 * yB + vB);
    float* E2 = (float*)(ws + fixedEnd + 2 * yB + 2 * vB);

    k_sums<<<dim3(1), dim3(256), 0, stream>>>(adj, cs, rs);
    k_lap<<<dim3((NN * NN + 255) / 256), dim3(256), 0, stream>>>(adj, cs, rs, L, Lt);
    k_sq<<<dim3((NN * NN + 255) / 256), dim3(256), 0, stream>>>(L, C2, C2T);
    k_wprep<<<dim3((KF * MC + 255) / 256), dim3(256), 0, stream>>>(w, Wm);

    for (int a0 = 0; a0 < 8; a0 += Ab) {
        for (int i0 = 0; i0 < NN; i0 += Gi) {
            k_y<<<dim3(50, (Gi + 31) / 32, Ab), dim3(256), 0, stream>>>(
                L, C2, x, Y1, Y2, a0, i0, Gi);
            k_mix2<<<dim3(7, Ab * Gi), dim3(256), 0, stream>>>(
                x, Y1, Y2, Wm, Dm, E1, E2, a0, i0, Gi);
            k_out<<<dim3(Ab * Gi), dim3(256), 0, stream>>>(
                Lt, C2T, Dm, E1, E2, bias, out, a0, i0, Gi);
        }
    }
}